// Round 14
// baseline (304.361 us; speedup 1.0000x reference)
//
#include <hip/hip_runtime.h>
#include <stdint.h>

#define DEVI __device__ __forceinline__

typedef __attribute__((ext_vector_type(8))) short bf16x8;
typedef __attribute__((ext_vector_type(4))) float f32x4;
typedef __attribute__((ext_vector_type(16))) float f32x16;
typedef __attribute__((ext_vector_type(4))) unsigned short u16x4;
typedef __attribute__((ext_vector_type(8))) unsigned short u16x8;

// round-to-nearest-even f32 -> bf16
DEVI unsigned short f2bf(float f) {
    union { float f; unsigned u; } v; v.f = f;
    unsigned r = v.u + 0x7fffu + ((v.u >> 16) & 1u);
    return (unsigned short)(r >> 16);
}

DEVI float bf2f(unsigned short u) {
    union { unsigned u; float f; } v; v.u = ((unsigned)u) << 16;
    return v.f;
}

// pack two f32 -> two bf16 in one dword (RNE), hw instruction
DEVI unsigned cvtpk(float lo, float hi) {
    unsigned r;
    asm("v_cvt_pk_bf16_f32 %0, %1, %2" : "=v"(r) : "v"(lo), "v"(hi));
    return r;
}

// async global->LDS, 16B per lane. LDS dest = wave-uniform base + lane*16.
DEVI void gload16(const void* g, void* lds) {
    __builtin_amdgcn_global_load_lds(
        (const __attribute__((address_space(1))) unsigned int*)(uintptr_t)g,
        (__attribute__((address_space(3))) unsigned int*)(unsigned int)(uintptr_t)lds,
        16, 0, 0);
}

// ------------------------------------------------ fused convert (one launch)
__global__ __launch_bounds__(256) void cvt_all(
    const float* __restrict__ hs, const float* __restrict__ wq,
    const float* __restrict__ wk, const float* __restrict__ wv,
    const float* __restrict__ wo,
    unsigned short* __restrict__ o_hs, unsigned short* __restrict__ o_wq,
    unsigned short* __restrict__ o_wk, unsigned short* __restrict__ o_wv,
    unsigned short* __restrict__ o_wo) {
    const int bid = blockIdx.x;
    const float* src; unsigned short* dst; int base;
    if (bid < 2048)      { src = hs; dst = o_hs; base = bid; }
    else if (bid < 3072) { src = wq; dst = o_wq; base = bid - 2048; }
    else if (bid < 4096) { src = wk; dst = o_wk; base = bid - 3072; }
    else if (bid < 5120) { src = wv; dst = o_wv; base = bid - 4096; }
    else                 { src = wo; dst = o_wo; base = bid - 5120; }
    const int i0 = base * 1024 + threadIdx.x;
#pragma unroll
    for (int k = 0; k < 4; k++) {
        const int i = i0 + k * 256;
        float4 v = ((const float4*)src)[i];
        u16x4 pk;
        pk[0] = f2bf(v.x); pk[1] = f2bf(v.y); pk[2] = f2bf(v.z); pk[3] = f2bf(v.w);
        ((u16x4*)dst)[i] = pk;
    }
}

// --------------------------------- 256x256 m201-style 8-phase GEMM core (qkv)
// 8 waves (2x4), per-wave 128x64 = acc[8][4]. 4 phases per K-tile (BK=64),
// each phase: {ds reads (ph0: 8 B + 4 A + lgkm(8); else 4 A) | 2 gloads |
// s_barrier | lgkm(0) | setprio + 16 MFMA + setprio | s_barrier}.
// B fragments held in regs across the tile. LDS 128KB: A 2x32KB + B 2x32KB.
// Stage plan + race ledger:
//   ph0/ph1: A(kt+1) halves -> parity kt+1, region free since kt-1 ph3 barrier.
//   ph2/ph3: B(kt+2) halves -> parity kt, B fully consumed at ph0 (all waves
//            past their lgkm(0) by ph0 end-barrier; ph2 body is after ph1 bar).
// Issue order B(kt+1) < A(kt+1) < B(kt+2) -> end-of-tile wait is a COUNTED
// vmcnt(4) (only B(kt+2)'s 4 loads may fly). kt==30: vmcnt(0) drain; kt==31: none.
// Prologue: A(0),B(0),B(1) then vmcnt(4).
DEVI void gemm_core256_8ph(const unsigned short* __restrict__ A,
                           const unsigned short* __restrict__ Wt,
                           int m0, int n0, char* lds,
                           f32x4 (&acc)[8][4]) {
    constexpr int K = 2048, NT = 32;
    const int t = threadIdx.x;
    const int w = t >> 6, l = t & 63, lr = l & 15, lk = l >> 4;
    const int wr = w >> 2, wc = w & 3;
    const int sx = lr & 7;
    const int srow = t >> 3, sseg = (t & 7) ^ (srow & 7);
    const unsigned short* aS = A + (size_t)(m0 + srow) * K + sseg * 8;
    const unsigned short* bS = Wt + (size_t)(n0 + srow) * K + sseg * 8;

#pragma unroll
    for (int mi = 0; mi < 8; mi++)
#pragma unroll
        for (int ni = 0; ni < 4; ni++) acc[mi][ni] = (f32x4){0.f, 0.f, 0.f, 0.f};

    auto STAGE_A = [&](int tt, int half) {   // 2 gloads = 128 rows (one half-tile)
        if (tt >= NT) return;
        const int k0 = tt * 64, bb = tt & 1;
        char* d = lds + bb * 32768 + half * 16384 + w * 1024;
        gload16(aS + (size_t)(half * 128) * K + k0, d);
        gload16(aS + (size_t)(half * 128 + 64) * K + k0, d + 8192);
    };
    auto STAGE_B = [&](int tt, int half) {
        if (tt >= NT) return;
        const int k0 = tt * 64, bb = tt & 1;
        char* d = lds + 65536 + bb * 32768 + half * 16384 + w * 1024;
        gload16(bS + (size_t)(half * 128) * K + k0, d);
        gload16(bS + (size_t)(half * 128 + 64) * K + k0, d + 8192);
    };

    // prologue: A(0), B(0), B(1); wait A(0),B(0) (B(1)'s 4 loads stay in flight)
    STAGE_A(0, 0); STAGE_A(0, 1);
    STAGE_B(0, 0); STAGE_B(0, 1);
    STAGE_B(1, 0); STAGE_B(1, 1);
    asm volatile("s_waitcnt vmcnt(4)" ::: "memory");
    __builtin_amdgcn_s_barrier();

    for (int kt = 0; kt < NT; ++kt) {
        const int bb = kt & 1;
        const char* Ab = lds + bb * 32768;
        const char* Bb = lds + 65536 + bb * 32768;
        bf16x8 b[4][2];
#pragma unroll
        for (int p = 0; p < 4; ++p) {
            bf16x8 a[2][2];
            if (p == 0) {
#pragma unroll
                for (int ni = 0; ni < 4; ni++)
#pragma unroll
                    for (int ks = 0; ks < 2; ks++)
                        b[ni][ks] = *(const bf16x8*)(Bb + (wc * 64 + ni * 16 + lr) * 128 +
                                                     (((ks * 4 + lk) ^ sx) << 4));
            }
#pragma unroll
            for (int mi = 0; mi < 2; mi++)
#pragma unroll
                for (int ks = 0; ks < 2; ks++)
                    a[mi][ks] = *(const bf16x8*)(Ab + (wr * 128 + (2 * p + mi) * 16 + lr) * 128 +
                                                 (((ks * 4 + lk) ^ sx) << 4));
            if (p == 0)      STAGE_A(kt + 1, 0);
            else if (p == 1) STAGE_A(kt + 1, 1);
            else if (p == 2) STAGE_B(kt + 2, 0);
            else             STAGE_B(kt + 2, 1);
            if (p == 0) asm volatile("s_waitcnt lgkmcnt(8)" ::: "memory");
            __builtin_amdgcn_s_barrier();
            asm volatile("s_waitcnt lgkmcnt(0)" ::: "memory");
            __builtin_amdgcn_s_setprio(1);
#pragma unroll
            for (int ks = 0; ks < 2; ks++)
#pragma unroll
                for (int mi = 0; mi < 2; mi++)
#pragma unroll
                    for (int ni = 0; ni < 4; ni++)
                        acc[2 * p + mi][ni] = __builtin_amdgcn_mfma_f32_16x16x32_bf16(
                            a[mi][ks], b[ni][ks], acc[2 * p + mi][ni], 0, 0, 0);
            __builtin_amdgcn_s_setprio(0);
            if (p == 3) {
                if (kt < 30)       asm volatile("s_waitcnt vmcnt(4)" ::: "memory");
                else if (kt == 30) asm volatile("s_waitcnt vmcnt(0)" ::: "memory");
            }
            __builtin_amdgcn_s_barrier();
        }
    }
}

// ------------------------------------------------------- 2-phase GEMM core
// round-9 128x256 version (proven; used by gemm_o: 256 blocks = 1 CU round).
DEVI void gemm_pipe_core(const unsigned short* __restrict__ A,
                         const unsigned short* __restrict__ Wt,
                         int m0, int n0, char* lds,
                         f32x4 (&acc)[2][2][2][2]) {
    constexpr int K = 2048;
    const int t = threadIdx.x;
    const int w = t >> 6, l = t & 63, lr = l & 15, lk = l >> 4;
    const int wr = w >> 2, wc = w & 3;
    const int sx = lr & 7;
    const int srow = t >> 3, sseg = (t & 7) ^ (srow & 7);
    const unsigned short* aS = A + (size_t)(m0 + srow) * K + sseg * 8;
    const unsigned short* bS = Wt + (size_t)(n0 + srow) * K + sseg * 8;
    char* Bbase = lds + 32768;

#pragma unroll
    for (int qm = 0; qm < 2; qm++)
#pragma unroll
        for (int qn = 0; qn < 2; qn++)
#pragma unroll
            for (int fr = 0; fr < 2; fr++)
#pragma unroll
                for (int fc = 0; fc < 2; fc++)
                    acc[qm][qn][fr][fc] = (f32x4){0.f, 0.f, 0.f, 0.f};

    auto STAGE = [&](int tt, int u) {
        if (tt >= 32) return;
        const int k0 = tt * 64, bb = tt & 1;
        if (u < 4)
            gload16(bS + (size_t)u * 64 * K + k0, Bbase + bb * 32768 + u * 8192 + w * 1024);
        else
            gload16(aS + (size_t)(u - 4) * 64 * K + k0, lds + bb * 16384 + (u - 4) * 8192 + w * 1024);
    };

    STAGE(0, 0); STAGE(0, 1); STAGE(0, 2); STAGE(0, 3); STAGE(0, 4); STAGE(0, 5);
    STAGE(1, 0); STAGE(1, 1); STAGE(1, 2);
    asm volatile("s_waitcnt vmcnt(3)" ::: "memory");
    __builtin_amdgcn_s_barrier();

    for (int kt = 0; kt < 32; ++kt) {
        const int bb = kt & 1;
        const char* Ab = lds + bb * 16384;
        const char* Bb = Bbase + bb * 32768;
        bf16x8 a0[2][2], a1[2][2], b0[2][2], b1[2][2];
#pragma unroll
        for (int fr = 0; fr < 2; fr++)
#pragma unroll
            for (int ks = 0; ks < 2; ks++) {
                a0[fr][ks] = *(const bf16x8*)(Ab + (wr * 64 + fr * 16 + lr) * 128 +
                                              (((ks * 4 + lk) ^ sx) << 4));
                a1[fr][ks] = *(const bf16x8*)(Ab + (wr * 64 + 32 + fr * 16 + lr) * 128 +
                                              (((ks * 4 + lk) ^ sx) << 4));
            }
#pragma unroll
        for (int fc = 0; fc < 2; fc++)
#pragma unroll
            for (int ks = 0; ks < 2; ks++) {
                b0[fc][ks] = *(const bf16x8*)(Bb + (wc * 64 + fc * 16 + lr) * 128 +
                                              (((ks * 4 + lk) ^ sx) << 4));
                b1[fc][ks] = *(const bf16x8*)(Bb + (wc * 64 + 32 + fc * 16 + lr) * 128 +
                                              (((ks * 4 + lk) ^ sx) << 4));
            }
        STAGE(kt + 1, 3); STAGE(kt + 1, 4); STAGE(kt + 1, 5);
        __builtin_amdgcn_s_setprio(1);
#pragma unroll
        for (int ks = 0; ks < 2; ks++)
#pragma unroll
            for (int fr = 0; fr < 2; fr++)
#pragma unroll
                for (int fc = 0; fc < 2; fc++) {
                    acc[0][0][fr][fc] = __builtin_amdgcn_mfma_f32_16x16x32_bf16(
                        a0[fr][ks], b0[fc][ks], acc[0][0][fr][fc], 0, 0, 0);
                    acc[1][0][fr][fc] = __builtin_amdgcn_mfma_f32_16x16x32_bf16(
                        a1[fr][ks], b0[fc][ks], acc[1][0][fr][fc], 0, 0, 0);
                }
        __builtin_amdgcn_s_setprio(0);
        asm volatile("s_waitcnt lgkmcnt(0)" ::: "memory");
        __builtin_amdgcn_s_barrier();
        STAGE(kt + 2, 0); STAGE(kt + 2, 1); STAGE(kt + 2, 2);
        __builtin_amdgcn_s_setprio(1);
#pragma unroll
        for (int ks = 0; ks < 2; ks++)
#pragma unroll
            for (int fr = 0; fr < 2; fr++)
#pragma unroll
                for (int fc = 0; fc < 2; fc++) {
                    acc[0][1][fr][fc] = __builtin_amdgcn_mfma_f32_16x16x32_bf16(
                        a0[fr][ks], b1[fc][ks], acc[0][1][fr][fc], 0, 0, 0);
                    acc[1][1][fr][fc] = __builtin_amdgcn_mfma_f32_16x16x32_bf16(
                        a1[fr][ks], b1[fc][ks], acc[1][1][fr][fc], 0, 0, 0);
                }
        __builtin_amdgcn_s_setprio(0);
        if (kt < 30)       asm volatile("s_waitcnt vmcnt(3)" ::: "memory");
        else if (kt == 30) asm volatile("s_waitcnt vmcnt(0)" ::: "memory");
        __builtin_amdgcn_s_barrier();
    }
}

// qkv (256x256 8-phase): z=0 -> q (bf16), z=1 -> k (bf16), z=2 -> v -> (B,H,HD,S)
__global__ __launch_bounds__(512, 2) void gemm_qkv(
    const unsigned short* __restrict__ A,
    const unsigned short* __restrict__ Wq16, const unsigned short* __restrict__ Wk16,
    const unsigned short* __restrict__ Wv16,
    const float* __restrict__ bq, const float* __restrict__ bk, const float* __restrict__ bv,
    unsigned short* __restrict__ qh, unsigned short* __restrict__ kh,
    unsigned short* __restrict__ Vt) {
    __shared__ char Lds[131072];
    const int bid = blockIdx.x;
    const int nt = bid & 7, idx = bid >> 3;
    const int mt = idx & 15, z = idx >> 4;
    const int m0 = mt * 256, n0 = nt * 256;
    const unsigned short* W = (z == 0) ? Wq16 : (z == 1) ? Wk16 : Wv16;
    const float* bias = (z == 0) ? bq : (z == 1) ? bk : bv;

    f32x4 acc[8][4];
    gemm_core256_8ph(A, W, m0, n0, Lds, acc);

    const int t = threadIdx.x, w = t >> 6, l = t & 63, lr = l & 15, lk = l >> 4;
    const int wr = w >> 2, wc = w & 3;
#pragma unroll
    for (int mi = 0; mi < 8; mi++)
#pragma unroll
        for (int ni = 0; ni < 4; ni++) {
            const int col = n0 + wc * 64 + ni * 16 + lr;
            const int rb = m0 + wr * 128 + mi * 16 + lk * 4;
            const float bb = bias[col];
            if (z == 2) {
                const int hh = col >> 7, d = col & 127;
                const int b = rb >> 11, s = rb & 2047;
                u16x4 pk;
#pragma unroll
                for (int j = 0; j < 4; j++) pk[j] = f2bf(acc[mi][ni][j] + bb);
                *(u16x4*)(Vt + ((size_t)((b * 16 + hh) * 128 + d)) * 2048 + s) = pk;
            } else {
                unsigned short* out = (z == 0) ? qh : kh;
#pragma unroll
                for (int j = 0; j < 4; j++)
                    out[(size_t)(rb + j) * 2048 + col] = f2bf(acc[mi][ni][j] + bb);
            }
        }
}

__global__ __launch_bounds__(512, 2) void gemm_o(
    const unsigned short* __restrict__ A, const unsigned short* __restrict__ W16,
    const float* __restrict__ bo, float* __restrict__ out) {
    __shared__ char Lds[98304];
    const int bid = blockIdx.x;
    const int nt = bid & 7, mt = bid >> 3;
    const int m0 = mt * 128, n0 = nt * 256;

    f32x4 acc[2][2][2][2];
    gemm_pipe_core(A, W16, m0, n0, Lds, acc);

    const int t = threadIdx.x, w = t >> 6, l = t & 63, lr = l & 15, lk = l >> 4;
    const int wr = w >> 2, wc = w & 3;
#pragma unroll
    for (int qm = 0; qm < 2; qm++)
#pragma unroll
        for (int qn = 0; qn < 2; qn++)
#pragma unroll
            for (int fr = 0; fr < 2; fr++)
#pragma unroll
                for (int fc = 0; fc < 2; fc++) {
                    const int col = n0 + wc * 64 + qn * 32 + fc * 16 + lr;
                    const int rb = m0 + wr * 64 + qm * 32 + fr * 16 + lk * 4;
                    const float bb = bo[col];
#pragma unroll
                    for (int j = 0; j < 4; j++)
                        out[(size_t)(rb + j) * 2048 + col] = acc[qm][qn][fr][fc][j] + bb;
                }
}

// ---------------------------------------------------- RMSNorm (full DIM) + RoPE
__global__ __launch_bounds__(256) void norm_rope(
    const unsigned short* __restrict__ qh, const unsigned short* __restrict__ kh,
    const float* __restrict__ nqw, const float* __restrict__ nkw,
    const float* __restrict__ fc, const float* __restrict__ fs,
    unsigned short* __restrict__ Qr, unsigned short* __restrict__ Kr) {
    const int row = blockIdx.x;
    const int which = blockIdx.y;
    const unsigned short* in = which ? kh : qh;
    const float* wv = which ? nkw : nqw;
    unsigned short* out = which ? Kr : Qr;
    const float qs = which ? 1.0f : 0.12751744f;  // 1/sqrt(128) * log2(e)
    const int t = threadIdx.x;
    u16x8 xr = *(const u16x8*)(in + (size_t)row * 2048 + t * 8);
    float xv[8];
#pragma unroll
    for (int e = 0; e < 8; e++) xv[e] = bf2f(xr[e]);
    float ss = 0.f;
#pragma unroll
    for (int e = 0; e < 8; e++) ss += xv[e] * xv[e];
#pragma unroll
    for (int m = 1; m < 64; m <<= 1) ss += __shfl_xor(ss, m, 64);
    __shared__ float red[4];
    if ((t & 63) == 0) red[t >> 6] = ss;
    __syncthreads();
    const float tot = red[0] + red[1] + red[2] + red[3];
    const float r = rsqrtf(tot * (1.0f / 2048.0f) + 1e-6f);
    const int s = row & 2047, b = row >> 11;
    const int d0 = t * 8, hd0 = d0 & 127, h = d0 >> 7;
    float4 c0 = ((const float4*)(fc + s * 128 + hd0))[0];
    float4 c1 = ((const float4*)(fc + s * 128 + hd0))[1];
    float4 s0 = ((const float4*)(fs + s * 128 + hd0))[0];
    float4 s1 = ((const float4*)(fs + s * 128 + hd0))[1];
    float4 w0 = ((const float4*)(wv + d0))[0];
    float4 w1 = ((const float4*)(wv + d0))[1];
    float wn[8] = {w0.x, w0.y, w0.z, w0.w, w1.x, w1.y, w1.z, w1.w};
    float xn[8];
#pragma unroll
    for (int e = 0; e < 8; e++) xn[e] = xv[e] * wn[e] * r;
    float o[8];
    o[0] = xn[0] * c0.x - xn[1] * s0.y;  o[1] = xn[0] * s0.y + xn[1] * c0.x;
    o[2] = xn[2] * c0.z - xn[3] * s0.w;  o[3] = xn[2] * s0.w + xn[3] * c0.z;
    o[4] = xn[4] * c1.x - xn[5] * s1.y;  o[5] = xn[4] * s1.y + xn[5] * c1.x;
    o[6] = xn[6] * c1.z - xn[7] * s1.w;  o[7] = xn[6] * s1.w + xn[7] * c1.z;
    u16x8 pk;
#pragma unroll
    for (int e = 0; e < 8; e++) pk[e] = f2bf(o[e] * qs);
    *(u16x8*)(out + ((size_t)((b * 16 + h) * 2048 + s)) * 128 + hd0) = pk;
}

// -------------------------------------------------------------- flash attn
// round-9 version (proven ~112us).
__global__ __launch_bounds__(256, 2) void attn(
    const unsigned short* __restrict__ Qr, const unsigned short* __restrict__ Kr,
    const unsigned short* __restrict__ Vt, unsigned short* __restrict__ Ao) {
    __shared__ unsigned short Kl[2][64 * 128];
    __shared__ unsigned short Vl[2][128 * 64];
    const int t = threadIdx.x, w = t >> 6, l = t & 63;
    const int ql = l & 31, h = l >> 5;
    const int bid = blockIdx.x;
    const int xcd = bid & 7, idx = bid >> 3;
    const int bh = xcd * 4 + (idx >> 4);
    const int q0 = (idx & 15) * 128 + w * 32;
    const int b = bh >> 4, head = bh & 15;

    const unsigned short* Qp = Qr + ((size_t)bh * 2048 + q0) * 128;
    bf16x8 qf[8];
#pragma unroll
    for (int c8 = 0; c8 < 8; c8++)
        qf[c8] = *(const bf16x8*)(Qp + ql * 128 + c8 * 16 + h * 8);

    f32x16 accO[4];
#pragma unroll
    for (int dt = 0; dt < 4; dt++)
#pragma unroll
        for (int r = 0; r < 16; r++) accO[dt][r] = 0.f;
    float mj = -1e30f, ljp = 0.f;

    const unsigned short* Kb = Kr + (size_t)bh * 2048 * 128;
    const unsigned short* Vb = Vt + (size_t)bh * 128 * 2048;
    const int krow = t >> 4, kseg = (t & 15) ^ (krow & 7);
    const int vrow = t >> 3, vseg = (t & 7) ^ (vrow & 7);

    auto STAGE = [&](int buf, int kv0) {
        char* kd = (char*)&Kl[buf][0] + w * 1024;
        char* vd = (char*)&Vl[buf][0] + w * 1024;
#pragma unroll
        for (int c = 0; c < 4; c++)
            gload16(Kb + (size_t)(kv0 + c * 16 + krow) * 128 + kseg * 8, kd + c * 4096);
#pragma unroll
        for (int c = 0; c < 4; c++)
            gload16(Vb + (size_t)(c * 32 + vrow) * 2048 + kv0 + vseg * 8, vd + c * 4096);
    };

    const int qx = ql & 7;
    STAGE(0, 0);
    __syncthreads();
    int cur = 0;
    for (int it = 0; it < 32; ++it) {
        if (it < 31) STAGE(cur ^ 1, (it + 1) * 64);
        f32x16 S0, S1;
#pragma unroll
        for (int r = 0; r < 16; r++) { S0[r] = 0.f; S1[r] = 0.f; }
        __builtin_amdgcn_s_setprio(1);
#pragma unroll
        for (int c8 = 0; c8 < 8; c8++) {
            const int sg = ((c8 * 2 + h) ^ qx) << 4;
            bf16x8 k0 = *(const bf16x8*)((const char*)&Kl[cur][0] + ql * 256 + sg);
            bf16x8 k1 = *(const bf16x8*)((const char*)&Kl[cur][0] + (32 + ql) * 256 + sg);
            S0 = __builtin_amdgcn_mfma_f32_32x32x16_bf16(k0, qf[c8], S0, 0, 0, 0);
            S1 = __builtin_amdgcn_mfma_f32_32x32x16_bf16(k1, qf[c8], S1, 0, 0, 0);
        }
        __builtin_amdgcn_s_setprio(0);
        float mloc = S0[0];
#pragma unroll
        for (int r = 1; r < 16; r++) mloc = fmaxf(mloc, S0[r]);
#pragma unroll
        for (int r = 0; r < 16; r++) mloc = fmaxf(mloc, S1[r]);
        const float mx = fmaxf(mloc, __shfl_xor(mloc, 32, 64));
        if (!__all(mx <= mj + 8.0f)) {          // T13 defer-max, THR=8
            const float mn = fmaxf(mj, mx);
            const float corr = exp2f(mj - mn);
            mj = mn;
            ljp *= corr;
#pragma unroll
            for (int dt = 0; dt < 4; dt++)
#pragma unroll
                for (int r = 0; r < 16; r++) accO[dt][r] *= corr;
        }
        unsigned W[16];
        float lsum = 0.f;
#pragma unroll
        for (int i = 0; i < 8; i++) {
            const float pa = exp2f(S0[2 * i] - mj);
            const float pb = exp2f(S0[2 * i + 1] - mj);
            W[i] = cvtpk(pa, pb);
            lsum += pa + pb;
        }
#pragma unroll
        for (int i = 0; i < 8; i++) {
            const float pa = exp2f(S1[2 * i] - mj);
            const float pb = exp2f(S1[2 * i + 1] - mj);
            W[8 + i] = cvtpk(pa, pb);
            lsum += pa + pb;
        }
        ljp += lsum;
#pragma unroll
        for (int c = 0; c < 2; c++) {
            unsigned X[8];
#pragma unroll
            for (int i = 0; i < 8; i++)
                X[i] = (unsigned)__shfl_xor((int)W[c * 8 + i], 32, 64);
            union U { unsigned u[4]; bf16x8 v; };
            U F, G;
            F.u[0] = h ? X[2] : W[c * 8 + 0];
            F.u[1] = h ? X[3] : W[c * 8 + 1];
            F.u[2] = h ? W[c * 8 + 2] : X[0];
            F.u[3] = h ? W[c * 8 + 3] : X[1];
            G.u[0] = h ? X[6] : W[c * 8 + 4];
            G.u[1] = h ? X[7] : W[c * 8 + 5];
            G.u[2] = h ? W[c * 8 + 6] : X[4];
            G.u[3] = h ? W[c * 8 + 7] : X[5];
            __builtin_amdgcn_s_setprio(1);
#pragma unroll
            for (int dt = 0; dt < 4; dt++) {
                const int sg = (((2 * c) * 2 + h) ^ qx) << 4;
                bf16x8 vf = *(const bf16x8*)((const char*)&Vl[cur][0] + (dt * 32 + ql) * 128 + sg);
                accO[dt] = __builtin_amdgcn_mfma_f32_32x32x16_bf16(vf, F.v, accO[dt], 0, 0, 0);
            }
#pragma unroll
            for (int dt = 0; dt < 4; dt++) {
                const int sg = (((2 * c + 1) * 2 + h) ^ qx) << 4;
                bf16x8 vf = *(const bf16x8*)((const char*)&Vl[cur][0] + (dt * 32 + ql) * 128 + sg);
                accO[dt] = __builtin_amdgcn_mfma_f32_32x32x16_bf16(vf, G.v, accO[dt], 0, 0, 0);
            }
            __builtin_amdgcn_s_setprio(0);
        }
        __syncthreads();
        cur ^= 1;
    }
    const float lj = ljp + __shfl_xor(ljp, 32, 64);
    const float inv = 1.0f / lj;
    unsigned short* ob = Ao + ((size_t)(b * 2048 + q0 + ql)) * 2048 + head * 128;
#pragma unroll
    for (int dt = 0; dt < 4; dt++)
#pragma unroll
        for (int i = 0; i < 8; i++) {
            const float a = accO[dt][2 * i] * inv;
            const float c = accO[dt][2 * i + 1] * inv;
            const int d = dt * 32 + ((2 * i) & 3) + 8 * (i >> 1) + 4 * h;
            *(unsigned*)(ob + d) = cvtpk(a, c);
        }
}

// ------------------------------------------------------------------ launch
extern "C" void kernel_launch(void* const* d_in, const int* in_sizes, int n_in,
                              void* d_out, int out_size, void* d_ws, size_t ws_size,
                              hipStream_t stream) {
    const float* hs  = (const float*)d_in[0];
    const float* fc  = (const float*)d_in[1];
    const float* fs  = (const float*)d_in[2];
    const float* Wq  = (const float*)d_in[3];
    const float* bq  = (const float*)d_in[4];
    const float* Wk  = (const float*)d_in[5];
    const float* bk  = (const float*)d_in[6];
    const float* Wv  = (const float*)d_in[7];
    const float* bv  = (const float*)d_in[8];
    const float* nqw = (const float*)d_in[9];
    const float* nkw = (const float*)d_in[10];
    const float* Wo  = (const float*)d_in[11];
    const float* bo  = (const float*)d_in[12];
    float* out = (float*)d_out;

    char* p = (char*)d_ws;
    unsigned short* hs16 = (unsigned short*)p; p += (size_t)8388608 * 2;
    unsigned short* Wq16 = (unsigned short*)p; p += (size_t)4194304 * 2;
    unsigned short* Wk16 = (unsigned short*)p; p += (size_t)4194304 * 2;
    unsigned short* Wv16 = (unsigned short*)p; p += (size_t)4194304 * 2;
    unsigned short* Wo16 = (unsigned short*)p; p += (size_t)4194304 * 2;
    unsigned short* qh = (unsigned short*)p;   p += (size_t)8388608 * 2;
    unsigned short* kh = (unsigned short*)p;   p += (size_t)8388608 * 2;
    unsigned short* Qr = (unsigned short*)p;   p += (size_t)8388608 * 2;
    unsigned short* Kr = (unsigned short*)p;   p += (size_t)8388608 * 2;
    unsigned short* Vt = (unsigned short*)p;   p += (size_t)8388608 * 2;
    unsigned short* Ao = (unsigned short*)p;   p += (size_t)8388608 * 2;
    (void)ws_size; (void)in_sizes; (void)n_in; (void)out_size;

    cvt_all<<<6144, 256, 0, stream>>>(hs, Wq, Wk, Wv, Wo,
                                      hs16, Wq16, Wk16, Wv16, Wo16);
    gemm_qkv<<<384, 512, 0, stream>>>(hs16, Wq16, Wk16, Wv16,
                                      bq, bk, bv, qh, kh, Vt);
    norm_rope<<<dim3(4096, 2), 256, 0, stream>>>(qh, kh, nqw, nkw, fc, fs, Qr, Kr);
    attn<<<512, 256, 0, stream>>>(Qr, Kr, Vt, Ao);
    gemm_o<<<256, 512, 0, stream>>>(Ao, Wo16, bo, out);
}

// Round 15
// 298.950 us; speedup vs baseline: 1.0181x; 1.0181x over previous
//
#include <hip/hip_runtime.h>
#include <stdint.h>

#define DEVI __device__ __forceinline__

typedef __attribute__((ext_vector_type(8))) short bf16x8;
typedef __attribute__((ext_vector_type(4))) float f32x4;
typedef __attribute__((ext_vector_type(16))) float f32x16;
typedef __attribute__((ext_vector_type(4))) unsigned short u16x4;
typedef __attribute__((ext_vector_type(8))) unsigned short u16x8;

// round-to-nearest-even f32 -> bf16
DEVI unsigned short f2bf(float f) {
    union { float f; unsigned u; } v; v.f = f;
    unsigned r = v.u + 0x7fffu + ((v.u >> 16) & 1u);
    return (unsigned short)(r >> 16);
}

DEVI float bf2f(unsigned short u) {
    union { unsigned u; float f; } v; v.u = ((unsigned)u) << 16;
    return v.f;
}

// pack two f32 -> two bf16 in one dword (RNE), hw instruction
DEVI unsigned cvtpk(float lo, float hi) {
    unsigned r;
    asm("v_cvt_pk_bf16_f32 %0, %1, %2" : "=v"(r) : "v"(lo), "v"(hi));
    return r;
}

// async global->LDS, 16B per lane. LDS dest = wave-uniform base + lane*16.
DEVI void gload16(const void* g, void* lds) {
    __builtin_amdgcn_global_load_lds(
        (const __attribute__((address_space(1))) unsigned int*)(uintptr_t)g,
        (__attribute__((address_space(3))) unsigned int*)(unsigned int)(uintptr_t)lds,
        16, 0, 0);
}

// ------------------------------------------------ fused convert (one launch)
__global__ __launch_bounds__(256) void cvt_all(
    const float* __restrict__ hs, const float* __restrict__ wq,
    const float* __restrict__ wk, const float* __restrict__ wv,
    const float* __restrict__ wo,
    unsigned short* __restrict__ o_hs, unsigned short* __restrict__ o_wq,
    unsigned short* __restrict__ o_wk, unsigned short* __restrict__ o_wv,
    unsigned short* __restrict__ o_wo) {
    const int bid = blockIdx.x;
    const float* src; unsigned short* dst; int base;
    if (bid < 2048)      { src = hs; dst = o_hs; base = bid; }
    else if (bid < 3072) { src = wq; dst = o_wq; base = bid - 2048; }
    else if (bid < 4096) { src = wk; dst = o_wk; base = bid - 3072; }
    else if (bid < 5120) { src = wv; dst = o_wv; base = bid - 4096; }
    else                 { src = wo; dst = o_wo; base = bid - 5120; }
    const int i0 = base * 1024 + threadIdx.x;
#pragma unroll
    for (int k = 0; k < 4; k++) {
        const int i = i0 + k * 256;
        float4 v = ((const float4*)src)[i];
        u16x4 pk;
        pk[0] = f2bf(v.x); pk[1] = f2bf(v.y); pk[2] = f2bf(v.z); pk[3] = f2bf(v.w);
        ((u16x4*)dst)[i] = pk;
    }
}

// ------------------------------------------------------- 2-phase GEMM core
// round-9 version: 113 us, MfmaUtil 39%, 0 bank conflicts. PROVEN LOCAL
// OPTIMUM — four structural variants all regressed (R5 4-phase: 121, R10
// 32x32-reads: 145, R13 256sq 2-phase: 122, R14 256sq 8-phase: 129.5).
DEVI void gemm_pipe_core(const unsigned short* __restrict__ A,
                         const unsigned short* __restrict__ Wt,
                         int m0, int n0, char* lds,
                         f32x4 (&acc)[2][2][2][2]) {
    constexpr int K = 2048;
    const int t = threadIdx.x;
    const int w = t >> 6, l = t & 63, lr = l & 15, lk = l >> 4;
    const int wr = w >> 2, wc = w & 3;
    const int sx = lr & 7;
    const int srow = t >> 3, sseg = (t & 7) ^ (srow & 7);
    const unsigned short* aS = A + (size_t)(m0 + srow) * K + sseg * 8;
    const unsigned short* bS = Wt + (size_t)(n0 + srow) * K + sseg * 8;
    char* Bbase = lds + 32768;

#pragma unroll
    for (int qm = 0; qm < 2; qm++)
#pragma unroll
        for (int qn = 0; qn < 2; qn++)
#pragma unroll
            for (int fr = 0; fr < 2; fr++)
#pragma unroll
                for (int fc = 0; fc < 2; fc++)
                    acc[qm][qn][fr][fc] = (f32x4){0.f, 0.f, 0.f, 0.f};

    auto STAGE = [&](int tt, int u) {
        if (tt >= 32) return;
        const int k0 = tt * 64, bb = tt & 1;
        if (u < 4)
            gload16(bS + (size_t)u * 64 * K + k0, Bbase + bb * 32768 + u * 8192 + w * 1024);
        else
            gload16(aS + (size_t)(u - 4) * 64 * K + k0, lds + bb * 16384 + (u - 4) * 8192 + w * 1024);
    };

    STAGE(0, 0); STAGE(0, 1); STAGE(0, 2); STAGE(0, 3); STAGE(0, 4); STAGE(0, 5);
    STAGE(1, 0); STAGE(1, 1); STAGE(1, 2);
    asm volatile("s_waitcnt vmcnt(3)" ::: "memory");
    __builtin_amdgcn_s_barrier();

    for (int kt = 0; kt < 32; ++kt) {
        const int bb = kt & 1;
        const char* Ab = lds + bb * 16384;
        const char* Bb = Bbase + bb * 32768;
        bf16x8 a0[2][2], a1[2][2], b0[2][2], b1[2][2];
#pragma unroll
        for (int fr = 0; fr < 2; fr++)
#pragma unroll
            for (int ks = 0; ks < 2; ks++) {
                a0[fr][ks] = *(const bf16x8*)(Ab + (wr * 64 + fr * 16 + lr) * 128 +
                                              (((ks * 4 + lk) ^ sx) << 4));
                a1[fr][ks] = *(const bf16x8*)(Ab + (wr * 64 + 32 + fr * 16 + lr) * 128 +
                                              (((ks * 4 + lk) ^ sx) << 4));
            }
#pragma unroll
        for (int fc = 0; fc < 2; fc++)
#pragma unroll
            for (int ks = 0; ks < 2; ks++) {
                b0[fc][ks] = *(const bf16x8*)(Bb + (wc * 64 + fc * 16 + lr) * 128 +
                                              (((ks * 4 + lk) ^ sx) << 4));
                b1[fc][ks] = *(const bf16x8*)(Bb + (wc * 64 + 32 + fc * 16 + lr) * 128 +
                                              (((ks * 4 + lk) ^ sx) << 4));
            }
        STAGE(kt + 1, 3); STAGE(kt + 1, 4); STAGE(kt + 1, 5);
        __builtin_amdgcn_s_setprio(1);
#pragma unroll
        for (int ks = 0; ks < 2; ks++)
#pragma unroll
            for (int fr = 0; fr < 2; fr++)
#pragma unroll
                for (int fc = 0; fc < 2; fc++) {
                    acc[0][0][fr][fc] = __builtin_amdgcn_mfma_f32_16x16x32_bf16(
                        a0[fr][ks], b0[fc][ks], acc[0][0][fr][fc], 0, 0, 0);
                    acc[1][0][fr][fc] = __builtin_amdgcn_mfma_f32_16x16x32_bf16(
                        a1[fr][ks], b0[fc][ks], acc[1][0][fr][fc], 0, 0, 0);
                }
        __builtin_amdgcn_s_setprio(0);
        asm volatile("s_waitcnt lgkmcnt(0)" ::: "memory");
        __builtin_amdgcn_s_barrier();
        STAGE(kt + 2, 0); STAGE(kt + 2, 1); STAGE(kt + 2, 2);
        __builtin_amdgcn_s_setprio(1);
#pragma unroll
        for (int ks = 0; ks < 2; ks++)
#pragma unroll
            for (int fr = 0; fr < 2; fr++)
#pragma unroll
                for (int fc = 0; fc < 2; fc++) {
                    acc[0][1][fr][fc] = __builtin_amdgcn_mfma_f32_16x16x32_bf16(
                        a0[fr][ks], b1[fc][ks], acc[0][1][fr][fc], 0, 0, 0);
                    acc[1][1][fr][fc] = __builtin_amdgcn_mfma_f32_16x16x32_bf16(
                        a1[fr][ks], b1[fc][ks], acc[1][1][fr][fc], 0, 0, 0);
                }
        __builtin_amdgcn_s_setprio(0);
        if (kt < 30)       asm volatile("s_waitcnt vmcnt(3)" ::: "memory");
        else if (kt == 30) asm volatile("s_waitcnt vmcnt(0)" ::: "memory");
        __builtin_amdgcn_s_barrier();
    }
}

// qkv: z=0 -> q (bf16), z=1 -> k (bf16), z=2 -> v (bf16, transposed (B,H,HD,S))
__global__ __launch_bounds__(512, 2) void gemm_qkv(
    const unsigned short* __restrict__ A,
    const unsigned short* __restrict__ Wq16, const unsigned short* __restrict__ Wk16,
    const unsigned short* __restrict__ Wv16,
    const float* __restrict__ bq, const float* __restrict__ bk, const float* __restrict__ bv,
    unsigned short* __restrict__ qh, unsigned short* __restrict__ kh,
    unsigned short* __restrict__ Vt) {
    __shared__ char Lds[98304];
    const int bid = blockIdx.x;
    const int nt = bid & 7, rem = bid >> 3;
    const int mt = rem / 3, z = rem % 3;
    const int m0 = mt * 128, n0 = nt * 256;
    const unsigned short* W = (z == 0) ? Wq16 : (z == 1) ? Wk16 : Wv16;
    const float* bias = (z == 0) ? bq : (z == 1) ? bk : bv;

    f32x4 acc[2][2][2][2];
    gemm_pipe_core(A, W, m0, n0, Lds, acc);

    const int t = threadIdx.x, w = t >> 6, l = t & 63, lr = l & 15, lk = l >> 4;
    const int wr = w >> 2, wc = w & 3;
#pragma unroll
    for (int qm = 0; qm < 2; qm++)
#pragma unroll
        for (int qn = 0; qn < 2; qn++)
#pragma unroll
            for (int fr = 0; fr < 2; fr++)
#pragma unroll
                for (int fc = 0; fc < 2; fc++) {
                    const int col = n0 + wc * 64 + qn * 32 + fc * 16 + lr;
                    const int rb = m0 + wr * 64 + qm * 32 + fr * 16 + lk * 4;
                    const float bb = bias[col];
                    if (z == 2) {
                        const int hh = col >> 7, d = col & 127;
                        const int b = rb >> 11, s = rb & 2047;
                        u16x4 pk;
#pragma unroll
                        for (int j = 0; j < 4; j++) pk[j] = f2bf(acc[qm][qn][fr][fc][j] + bb);
                        *(u16x4*)(Vt + ((size_t)((b * 16 + hh) * 128 + d)) * 2048 + s) = pk;
                    } else {
                        unsigned short* out = (z == 0) ? qh : kh;
#pragma unroll
                        for (int j = 0; j < 4; j++)
                            out[(size_t)(rb + j) * 2048 + col] = f2bf(acc[qm][qn][fr][fc][j] + bb);
                    }
                }
}

__global__ __launch_bounds__(512, 2) void gemm_o(
    const unsigned short* __restrict__ A, const unsigned short* __restrict__ W16,
    const float* __restrict__ bo, float* __restrict__ out) {
    __shared__ char Lds[98304];
    const int bid = blockIdx.x;
    const int nt = bid & 7, mt = bid >> 3;
    const int m0 = mt * 128, n0 = nt * 256;

    f32x4 acc[2][2][2][2];
    gemm_pipe_core(A, W16, m0, n0, Lds, acc);

    const int t = threadIdx.x, w = t >> 6, l = t & 63, lr = l & 15, lk = l >> 4;
    const int wr = w >> 2, wc = w & 3;
#pragma unroll
    for (int qm = 0; qm < 2; qm++)
#pragma unroll
        for (int qn = 0; qn < 2; qn++)
#pragma unroll
            for (int fr = 0; fr < 2; fr++)
#pragma unroll
                for (int fc = 0; fc < 2; fc++) {
                    const int col = n0 + wc * 64 + qn * 32 + fc * 16 + lr;
                    const int rb = m0 + wr * 64 + qm * 32 + fr * 16 + lk * 4;
                    const float bb = bo[col];
#pragma unroll
                    for (int j = 0; j < 4; j++)
                        out[(size_t)(rb + j) * 2048 + col] = acc[qm][qn][fr][fc][j] + bb;
                }
}

// ---------------------------------------------------- RMSNorm (full DIM) + RoPE
__global__ __launch_bounds__(256) void norm_rope(
    const unsigned short* __restrict__ qh, const unsigned short* __restrict__ kh,
    const float* __restrict__ nqw, const float* __restrict__ nkw,
    const float* __restrict__ fc, const float* __restrict__ fs,
    unsigned short* __restrict__ Qr, unsigned short* __restrict__ Kr) {
    const int row = blockIdx.x;
    const int which = blockIdx.y;
    const unsigned short* in = which ? kh : qh;
    const float* wv = which ? nkw : nqw;
    unsigned short* out = which ? Kr : Qr;
    const float qs = which ? 1.0f : 0.12751744f;  // 1/sqrt(128) * log2(e)
    const int t = threadIdx.x;
    u16x8 xr = *(const u16x8*)(in + (size_t)row * 2048 + t * 8);
    float xv[8];
#pragma unroll
    for (int e = 0; e < 8; e++) xv[e] = bf2f(xr[e]);
    float ss = 0.f;
#pragma unroll
    for (int e = 0; e < 8; e++) ss += xv[e] * xv[e];
#pragma unroll
    for (int m = 1; m < 64; m <<= 1) ss += __shfl_xor(ss, m, 64);
    __shared__ float red[4];
    if ((t & 63) == 0) red[t >> 6] = ss;
    __syncthreads();
    const float tot = red[0] + red[1] + red[2] + red[3];
    const float r = rsqrtf(tot * (1.0f / 2048.0f) + 1e-6f);
    const int s = row & 2047, b = row >> 11;
    const int d0 = t * 8, hd0 = d0 & 127, h = d0 >> 7;
    float4 c0 = ((const float4*)(fc + s * 128 + hd0))[0];
    float4 c1 = ((const float4*)(fc + s * 128 + hd0))[1];
    float4 s0 = ((const float4*)(fs + s * 128 + hd0))[0];
    float4 s1 = ((const float4*)(fs + s * 128 + hd0))[1];
    float4 w0 = ((const float4*)(wv + d0))[0];
    float4 w1 = ((const float4*)(wv + d0))[1];
    float wn[8] = {w0.x, w0.y, w0.z, w0.w, w1.x, w1.y, w1.z, w1.w};
    float xn[8];
#pragma unroll
    for (int e = 0; e < 8; e++) xn[e] = xv[e] * wn[e] * r;
    float o[8];
    o[0] = xn[0] * c0.x - xn[1] * s0.y;  o[1] = xn[0] * s0.y + xn[1] * c0.x;
    o[2] = xn[2] * c0.z - xn[3] * s0.w;  o[3] = xn[2] * s0.w + xn[3] * c0.z;
    o[4] = xn[4] * c1.x - xn[5] * s1.y;  o[5] = xn[4] * s1.y + xn[5] * c1.x;
    o[6] = xn[6] * c1.z - xn[7] * s1.w;  o[7] = xn[6] * s1.w + xn[7] * c1.z;
    u16x8 pk;
#pragma unroll
    for (int e = 0; e < 8; e++) pk[e] = f2bf(o[e] * qs);
    *(u16x8*)(out + ((size_t)((b * 16 + h) * 2048 + s)) * 128 + hd0) = pk;
}

// -------------------------------------------------------------- flash attn
// round-9/12 version (proven ~112us): 4 waves x 32 q-rows, 512 blocks -> 2
// de-phased blocks/CU; K+V double-buffered; __syncthreads per tile;
// swapped-QK 32x32x16 MFMA; lane<->lane+32 via __shfl_xor.
// Only delta vs R12: balanced max3-friendly reduction tree (same math,
// dep-chain 32 -> 6).
__global__ __launch_bounds__(256, 2) void attn(
    const unsigned short* __restrict__ Qr, const unsigned short* __restrict__ Kr,
    const unsigned short* __restrict__ Vt, unsigned short* __restrict__ Ao) {
    __shared__ unsigned short Kl[2][64 * 128];
    __shared__ unsigned short Vl[2][128 * 64];
    const int t = threadIdx.x, w = t >> 6, l = t & 63;
    const int ql = l & 31, h = l >> 5;
    const int bid = blockIdx.x;
    const int xcd = bid & 7, idx = bid >> 3;
    const int bh = xcd * 4 + (idx >> 4);
    const int q0 = (idx & 15) * 128 + w * 32;
    const int b = bh >> 4, head = bh & 15;

    const unsigned short* Qp = Qr + ((size_t)bh * 2048 + q0) * 128;
    bf16x8 qf[8];
#pragma unroll
    for (int c8 = 0; c8 < 8; c8++)
        qf[c8] = *(const bf16x8*)(Qp + ql * 128 + c8 * 16 + h * 8);

    f32x16 accO[4];
#pragma unroll
    for (int dt = 0; dt < 4; dt++)
#pragma unroll
        for (int r = 0; r < 16; r++) accO[dt][r] = 0.f;
    float mj = -1e30f, ljp = 0.f;

    const unsigned short* Kb = Kr + (size_t)bh * 2048 * 128;
    const unsigned short* Vb = Vt + (size_t)bh * 128 * 2048;
    const int krow = t >> 4, kseg = (t & 15) ^ (krow & 7);
    const int vrow = t >> 3, vseg = (t & 7) ^ (vrow & 7);

    auto STAGE = [&](int buf, int kv0) {
        char* kd = (char*)&Kl[buf][0] + w * 1024;
        char* vd = (char*)&Vl[buf][0] + w * 1024;
#pragma unroll
        for (int c = 0; c < 4; c++)
            gload16(Kb + (size_t)(kv0 + c * 16 + krow) * 128 + kseg * 8, kd + c * 4096);
#pragma unroll
        for (int c = 0; c < 4; c++)
            gload16(Vb + (size_t)(c * 32 + vrow) * 2048 + kv0 + vseg * 8, vd + c * 4096);
    };

    const int qx = ql & 7;
    STAGE(0, 0);
    __syncthreads();
    int cur = 0;
    for (int it = 0; it < 32; ++it) {
        if (it < 31) STAGE(cur ^ 1, (it + 1) * 64);
        f32x16 S0, S1;
#pragma unroll
        for (int r = 0; r < 16; r++) { S0[r] = 0.f; S1[r] = 0.f; }
        __builtin_amdgcn_s_setprio(1);
#pragma unroll
        for (int c8 = 0; c8 < 8; c8++) {
            const int sg = ((c8 * 2 + h) ^ qx) << 4;
            bf16x8 k0 = *(const bf16x8*)((const char*)&Kl[cur][0] + ql * 256 + sg);
            bf16x8 k1 = *(const bf16x8*)((const char*)&Kl[cur][0] + (32 + ql) * 256 + sg);
            S0 = __builtin_amdgcn_mfma_f32_32x32x16_bf16(k0, qf[c8], S0, 0, 0, 0);
            S1 = __builtin_amdgcn_mfma_f32_32x32x16_bf16(k1, qf[c8], S1, 0, 0, 0);
        }
        __builtin_amdgcn_s_setprio(0);
        // balanced max tree (same result as serial chain; max3-fusable)
        float tq[8];
#pragma unroll
        for (int i = 0; i < 8; i++)
            tq[i] = fmaxf(fmaxf(S0[2 * i], S0[2 * i + 1]),
                          fmaxf(S1[2 * i], S1[2 * i + 1]));
        const float mloc = fmaxf(
            fmaxf(fmaxf(tq[0], tq[1]), fmaxf(tq[2], tq[3])),
            fmaxf(fmaxf(tq[4], tq[5]), fmaxf(tq[6], tq[7])));
        const float mx = fmaxf(mloc, __shfl_xor(mloc, 32, 64));
        if (!__all(mx <= mj + 8.0f)) {          // T13 defer-max, THR=8
            const float mn = fmaxf(mj, mx);
            const float corr = exp2f(mj - mn);
            mj = mn;
            ljp *= corr;
#pragma unroll
            for (int dt = 0; dt < 4; dt++)
#pragma unroll
                for (int r = 0; r < 16; r++) accO[dt][r] *= corr;
        }
        unsigned W[16];
        float lsum = 0.f;
#pragma unroll
        for (int i = 0; i < 8; i++) {
            const float pa = exp2f(S0[2 * i] - mj);
            const float pb = exp2f(S0[2 * i + 1] - mj);
            W[i] = cvtpk(pa, pb);
            lsum += pa + pb;
        }
#pragma unroll
        for (int i = 0; i < 8; i++) {
            const float pa = exp2f(S1[2 * i] - mj);
            const float pb = exp2f(S1[2 * i + 1] - mj);
            W[8 + i] = cvtpk(pa, pb);
            lsum += pa + pb;
        }
        ljp += lsum;
#pragma unroll
        for (int c = 0; c < 2; c++) {
            unsigned X[8];
#pragma unroll
            for (int i = 0; i < 8; i++)
                X[i] = (unsigned)__shfl_xor((int)W[c * 8 + i], 32, 64);
            union U { unsigned u[4]; bf16x8 v; };
            U F, G;
            F.u[0] = h ? X[2] : W[c * 8 + 0];
            F.u[1] = h ? X[3] : W[c * 8 + 1];
            F.u[2] = h ? W[c * 8 + 2] : X[0];
            F.u[3] = h ? W[c * 8 + 3] : X[1];
            G.u[0] = h ? X[6] : W[c * 8 + 4];
            G.u[1] = h ? X[7] : W[c * 8 + 5];
            G.u[2] = h ? W[c * 8 + 6] : X[4];
            G.u[3] = h ? W[c * 8 + 7] : X[5];
            __builtin_amdgcn_s_setprio(1);
#pragma unroll
            for (int dt = 0; dt < 4; dt++) {
                const int sg = (((2 * c) * 2 + h) ^ qx) << 4;
                bf16x8 vf = *(const bf16x8*)((const char*)&Vl[cur][0] + (dt * 32 + ql) * 128 + sg);
                accO[dt] = __builtin_amdgcn_mfma_f32_32x32x16_bf16(vf, F.v, accO[dt], 0, 0, 0);
            }
#pragma unroll
            for (int dt = 0; dt < 4; dt++) {
                const int sg = (((2 * c + 1) * 2 + h) ^ qx) << 4;
                bf16x8 vf = *(const bf16x8*)((const char*)&Vl[cur][0] + (dt * 32 + ql) * 128 + sg);
                accO[dt] = __builtin_amdgcn_mfma_f32_32x32x16_bf16(vf, G.v, accO[dt], 0, 0, 0);
            }
            __builtin_amdgcn_s_setprio(0);
        }
        __syncthreads();
        cur ^= 1;
    }
    const float lj = ljp + __shfl_xor(ljp, 32, 64);
    const float inv = 1.0f / lj;
    unsigned short* ob = Ao + ((size_t)(b * 2048 + q0 + ql)) * 2048 + head * 128;
#pragma unroll
    for (int dt = 0; dt < 4; dt++)
#pragma unroll
        for (int i = 0; i < 8; i++) {
            const float a = accO[dt][2 * i] * inv;
            const float c = accO[dt][2 * i + 1] * inv;
            const int d = dt * 32 + ((2 * i) & 3) + 8 * (i >> 1) + 4 * h;
            *(unsigned*)(ob + d) = cvtpk(a, c);
        }
}

// ------------------------------------------------------------------ launch
extern "C" void kernel_launch(void* const* d_in, const int* in_sizes, int n_in,
                              void* d_out, int out_size, void* d_ws, size_t ws_size,
                              hipStream_t stream) {
    const float* hs  = (const float*)d_in[0];
    const float* fc  = (const float*)d_in[1];
    const float* fs  = (const float*)d_in[2];
    const float* Wq  = (const float*)d_in[3];
    const float* bq  = (const float*)d_in[4];
    const float* Wk  = (const float*)d_in[5];
    const float* bk  = (const float*)d_in[6];
    const float* Wv  = (const float*)d_in[7];
    const float* bv  = (const float*)d_in[8];
    const float* nqw = (const float*)d_in[9];
    const float* nkw = (const float*)d_in[10];
    const float* Wo  = (const float*)d_in[11];
    const float* bo  = (const float*)d_in[12];
    float* out = (float*)d_out;

    char* p = (char*)d_ws;
    unsigned short* hs16 = (unsigned short*)p; p += (size_t)8388608 * 2;
    unsigned short* Wq16 = (unsigned short*)p; p += (size_t)4194304 * 2;
    unsigned short* Wk16 = (unsigned short*)p; p += (size_t)4194304 * 2;
    unsigned short* Wv16 = (unsigned short*)p; p += (size_t)4194304 * 2;
    unsigned short* Wo16 = (unsigned short*)p; p += (size_t)4194304 * 2;
    unsigned short* qh = (unsigned short*)p;   p += (size_t)8388608 * 2;
    unsigned short* kh = (unsigned short*)p;   p += (size_t)8388608 * 2;
    unsigned short* Qr = (unsigned short*)p;   p += (size_t)8388608 * 2;
    unsigned short* Kr = (unsigned short*)p;   p += (size_t)8388608 * 2;
    unsigned short* Vt = (unsigned short*)p;   p += (size_t)8388608 * 2;
    unsigned short* Ao = (unsigned short*)p;   p += (size_t)8388608 * 2;
    (void)ws_size; (void)in_sizes; (void)n_in; (void)out_size;

    cvt_all<<<6144, 256, 0, stream>>>(hs, Wq, Wk, Wv, Wo,
                                      hs16, Wq16, Wk16, Wv16, Wo16);
    gemm_qkv<<<768, 512, 0, stream>>>(hs16, Wq16, Wk16, Wv16,
                                      bq, bk, bv, qh, kh, Vt);
    norm_rope<<<dim3(4096, 2), 256, 0, stream>>>(qh, kh, nqw, nkw, fc, fs, Qr, Kr);
    attn<<<512, 256, 0, stream>>>(Qr, Kr, Vt, Ao);
    gemm_o<<<256, 512, 0, stream>>>(Ao, Wo16, bo, out);
}

// Round 16
// 289.254 us; speedup vs baseline: 1.0522x; 1.0335x over previous
//
#include <hip/hip_runtime.h>
#include <stdint.h>

#define DEVI __device__ __forceinline__

typedef __attribute__((ext_vector_type(8))) short bf16x8;
typedef __attribute__((ext_vector_type(4))) float f32x4;
typedef __attribute__((ext_vector_type(16))) float f32x16;
typedef __attribute__((ext_vector_type(4))) unsigned short u16x4;
typedef __attribute__((ext_vector_type(8))) unsigned short u16x8;

// round-to-nearest-even f32 -> bf16
DEVI unsigned short f2bf(float f) {
    union { float f; unsigned u; } v; v.f = f;
    unsigned r = v.u + 0x7fffu + ((v.u >> 16) & 1u);
    return (unsigned short)(r >> 16);
}

DEVI float bf2f(unsigned short u) {
    union { unsigned u; float f; } v; v.u = ((unsigned)u) << 16;
    return v.f;
}

// pack two f32 -> two bf16 in one dword (RNE), hw instruction
DEVI unsigned cvtpk(float lo, float hi) {
    unsigned r;
    asm("v_cvt_pk_bf16_f32 %0, %1, %2" : "=v"(r) : "v"(lo), "v"(hi));
    return r;
}

// async global->LDS, 16B per lane. LDS dest = wave-uniform base + lane*16.
DEVI void gload16(const void* g, void* lds) {
    __builtin_amdgcn_global_load_lds(
        (const __attribute__((address_space(1))) unsigned int*)(uintptr_t)g,
        (__attribute__((address_space(3))) unsigned int*)(unsigned int)(uintptr_t)lds,
        16, 0, 0);
}

// ------------------------------------------------ fused convert (one launch)
__global__ __launch_bounds__(256) void cvt_all(
    const float* __restrict__ hs, const float* __restrict__ wq,
    const float* __restrict__ wk, const float* __restrict__ wv,
    const float* __restrict__ wo,
    unsigned short* __restrict__ o_hs, unsigned short* __restrict__ o_wq,
    unsigned short* __restrict__ o_wk, unsigned short* __restrict__ o_wv,
    unsigned short* __restrict__ o_wo) {
    const int bid = blockIdx.x;
    const float* src; unsigned short* dst; int base;
    if (bid < 2048)      { src = hs; dst = o_hs; base = bid; }
    else if (bid < 3072) { src = wq; dst = o_wq; base = bid - 2048; }
    else if (bid < 4096) { src = wk; dst = o_wk; base = bid - 3072; }
    else if (bid < 5120) { src = wv; dst = o_wv; base = bid - 4096; }
    else                 { src = wo; dst = o_wo; base = bid - 5120; }
    const int i0 = base * 1024 + threadIdx.x;
#pragma unroll
    for (int k = 0; k < 4; k++) {
        const int i = i0 + k * 256;
        float4 v = ((const float4*)src)[i];
        u16x4 pk;
        pk[0] = f2bf(v.x); pk[1] = f2bf(v.y); pk[2] = f2bf(v.z); pk[3] = f2bf(v.w);
        ((u16x4*)dst)[i] = pk;
    }
}

// ------------------------------------------------------- 2-phase GEMM core
// round-9 version: 113 us, MfmaUtil 39%, 0 bank conflicts. PROVEN LOCAL
// OPTIMUM — four structural variants all regressed.
DEVI void gemm_pipe_core(const unsigned short* __restrict__ A,
                         const unsigned short* __restrict__ Wt,
                         int m0, int n0, char* lds,
                         f32x4 (&acc)[2][2][2][2]) {
    constexpr int K = 2048;
    const int t = threadIdx.x;
    const int w = t >> 6, l = t & 63, lr = l & 15, lk = l >> 4;
    const int wr = w >> 2, wc = w & 3;
    const int sx = lr & 7;
    const int srow = t >> 3, sseg = (t & 7) ^ (srow & 7);
    const unsigned short* aS = A + (size_t)(m0 + srow) * K + sseg * 8;
    const unsigned short* bS = Wt + (size_t)(n0 + srow) * K + sseg * 8;
    char* Bbase = lds + 32768;

#pragma unroll
    for (int qm = 0; qm < 2; qm++)
#pragma unroll
        for (int qn = 0; qn < 2; qn++)
#pragma unroll
            for (int fr = 0; fr < 2; fr++)
#pragma unroll
                for (int fc = 0; fc < 2; fc++)
                    acc[qm][qn][fr][fc] = (f32x4){0.f, 0.f, 0.f, 0.f};

    auto STAGE = [&](int tt, int u) {
        if (tt >= 32) return;
        const int k0 = tt * 64, bb = tt & 1;
        if (u < 4)
            gload16(bS + (size_t)u * 64 * K + k0, Bbase + bb * 32768 + u * 8192 + w * 1024);
        else
            gload16(aS + (size_t)(u - 4) * 64 * K + k0, lds + bb * 16384 + (u - 4) * 8192 + w * 1024);
    };

    STAGE(0, 0); STAGE(0, 1); STAGE(0, 2); STAGE(0, 3); STAGE(0, 4); STAGE(0, 5);
    STAGE(1, 0); STAGE(1, 1); STAGE(1, 2);
    asm volatile("s_waitcnt vmcnt(3)" ::: "memory");
    __builtin_amdgcn_s_barrier();

    for (int kt = 0; kt < 32; ++kt) {
        const int bb = kt & 1;
        const char* Ab = lds + bb * 16384;
        const char* Bb = Bbase + bb * 32768;
        bf16x8 a0[2][2], a1[2][2], b0[2][2], b1[2][2];
#pragma unroll
        for (int fr = 0; fr < 2; fr++)
#pragma unroll
            for (int ks = 0; ks < 2; ks++) {
                a0[fr][ks] = *(const bf16x8*)(Ab + (wr * 64 + fr * 16 + lr) * 128 +
                                              (((ks * 4 + lk) ^ sx) << 4));
                a1[fr][ks] = *(const bf16x8*)(Ab + (wr * 64 + 32 + fr * 16 + lr) * 128 +
                                              (((ks * 4 + lk) ^ sx) << 4));
            }
#pragma unroll
        for (int fc = 0; fc < 2; fc++)
#pragma unroll
            for (int ks = 0; ks < 2; ks++) {
                b0[fc][ks] = *(const bf16x8*)(Bb + (wc * 64 + fc * 16 + lr) * 128 +
                                              (((ks * 4 + lk) ^ sx) << 4));
                b1[fc][ks] = *(const bf16x8*)(Bb + (wc * 64 + 32 + fc * 16 + lr) * 128 +
                                              (((ks * 4 + lk) ^ sx) << 4));
            }
        STAGE(kt + 1, 3); STAGE(kt + 1, 4); STAGE(kt + 1, 5);
        __builtin_amdgcn_s_setprio(1);
#pragma unroll
        for (int ks = 0; ks < 2; ks++)
#pragma unroll
            for (int fr = 0; fr < 2; fr++)
#pragma unroll
                for (int fc = 0; fc < 2; fc++) {
                    acc[0][0][fr][fc] = __builtin_amdgcn_mfma_f32_16x16x32_bf16(
                        a0[fr][ks], b0[fc][ks], acc[0][0][fr][fc], 0, 0, 0);
                    acc[1][0][fr][fc] = __builtin_amdgcn_mfma_f32_16x16x32_bf16(
                        a1[fr][ks], b0[fc][ks], acc[1][0][fr][fc], 0, 0, 0);
                }
        __builtin_amdgcn_s_setprio(0);
        asm volatile("s_waitcnt lgkmcnt(0)" ::: "memory");
        __builtin_amdgcn_s_barrier();
        STAGE(kt + 2, 0); STAGE(kt + 2, 1); STAGE(kt + 2, 2);
        __builtin_amdgcn_s_setprio(1);
#pragma unroll
        for (int ks = 0; ks < 2; ks++)
#pragma unroll
            for (int fr = 0; fr < 2; fr++)
#pragma unroll
                for (int fc = 0; fc < 2; fc++) {
                    acc[0][1][fr][fc] = __builtin_amdgcn_mfma_f32_16x16x32_bf16(
                        a0[fr][ks], b1[fc][ks], acc[0][1][fr][fc], 0, 0, 0);
                    acc[1][1][fr][fc] = __builtin_amdgcn_mfma_f32_16x16x32_bf16(
                        a1[fr][ks], b1[fc][ks], acc[1][1][fr][fc], 0, 0, 0);
                }
        __builtin_amdgcn_s_setprio(0);
        if (kt < 30)       asm volatile("s_waitcnt vmcnt(3)" ::: "memory");
        else if (kt == 30) asm volatile("s_waitcnt vmcnt(0)" ::: "memory");
        __builtin_amdgcn_s_barrier();
    }
}

// qkv: z=0 -> q (bf16), z=1 -> k (bf16), z=2 -> v (bf16, transposed (B,H,HD,S))
__global__ __launch_bounds__(512, 2) void gemm_qkv(
    const unsigned short* __restrict__ A,
    const unsigned short* __restrict__ Wq16, const unsigned short* __restrict__ Wk16,
    const unsigned short* __restrict__ Wv16,
    const float* __restrict__ bq, const float* __restrict__ bk, const float* __restrict__ bv,
    unsigned short* __restrict__ qh, unsigned short* __restrict__ kh,
    unsigned short* __restrict__ Vt) {
    __shared__ char Lds[98304];
    const int bid = blockIdx.x;
    const int nt = bid & 7, rem = bid >> 3;
    const int mt = rem / 3, z = rem % 3;
    const int m0 = mt * 128, n0 = nt * 256;
    const unsigned short* W = (z == 0) ? Wq16 : (z == 1) ? Wk16 : Wv16;
    const float* bias = (z == 0) ? bq : (z == 1) ? bk : bv;

    f32x4 acc[2][2][2][2];
    gemm_pipe_core(A, W, m0, n0, Lds, acc);

    const int t = threadIdx.x, w = t >> 6, l = t & 63, lr = l & 15, lk = l >> 4;
    const int wr = w >> 2, wc = w & 3;
#pragma unroll
    for (int qm = 0; qm < 2; qm++)
#pragma unroll
        for (int qn = 0; qn < 2; qn++)
#pragma unroll
            for (int fr = 0; fr < 2; fr++)
#pragma unroll
                for (int fc = 0; fc < 2; fc++) {
                    const int col = n0 + wc * 64 + qn * 32 + fc * 16 + lr;
                    const int rb = m0 + wr * 64 + qm * 32 + fr * 16 + lk * 4;
                    const float bb = bias[col];
                    if (z == 2) {
                        const int hh = col >> 7, d = col & 127;
                        const int b = rb >> 11, s = rb & 2047;
                        u16x4 pk;
#pragma unroll
                        for (int j = 0; j < 4; j++) pk[j] = f2bf(acc[qm][qn][fr][fc][j] + bb);
                        *(u16x4*)(Vt + ((size_t)((b * 16 + hh) * 128 + d)) * 2048 + s) = pk;
                    } else {
                        unsigned short* out = (z == 0) ? qh : kh;
#pragma unroll
                        for (int j = 0; j < 4; j++)
                            out[(size_t)(rb + j) * 2048 + col] = f2bf(acc[qm][qn][fr][fc][j] + bb);
                    }
                }
}

__global__ __launch_bounds__(512, 2) void gemm_o(
    const unsigned short* __restrict__ A, const unsigned short* __restrict__ W16,
    const float* __restrict__ bo, float* __restrict__ out) {
    __shared__ char Lds[98304];
    const int bid = blockIdx.x;
    const int nt = bid & 7, mt = bid >> 3;
    const int m0 = mt * 128, n0 = nt * 256;

    f32x4 acc[2][2][2][2];
    gemm_pipe_core(A, W16, m0, n0, Lds, acc);

    const int t = threadIdx.x, w = t >> 6, l = t & 63, lr = l & 15, lk = l >> 4;
    const int wr = w >> 2, wc = w & 3;
#pragma unroll
    for (int qm = 0; qm < 2; qm++)
#pragma unroll
        for (int qn = 0; qn < 2; qn++)
#pragma unroll
            for (int fr = 0; fr < 2; fr++)
#pragma unroll
                for (int fc = 0; fc < 2; fc++) {
                    const int col = n0 + wc * 64 + qn * 32 + fc * 16 + lr;
                    const int rb = m0 + wr * 64 + qm * 32 + fr * 16 + lk * 4;
                    const float bb = bo[col];
#pragma unroll
                    for (int j = 0; j < 4; j++)
                        out[(size_t)(rb + j) * 2048 + col] = acc[qm][qn][fr][fc][j] + bb;
                }
}

// ---------------------------------------------------- RMSNorm (full DIM) + RoPE
__global__ __launch_bounds__(256) void norm_rope(
    const unsigned short* __restrict__ qh, const unsigned short* __restrict__ kh,
    const float* __restrict__ nqw, const float* __restrict__ nkw,
    const float* __restrict__ fc, const float* __restrict__ fs,
    unsigned short* __restrict__ Qr, unsigned short* __restrict__ Kr) {
    const int row = blockIdx.x;
    const int which = blockIdx.y;
    const unsigned short* in = which ? kh : qh;
    const float* wv = which ? nkw : nqw;
    unsigned short* out = which ? Kr : Qr;
    const float qs = which ? 1.0f : 0.12751744f;  // 1/sqrt(128) * log2(e)
    const int t = threadIdx.x;
    u16x8 xr = *(const u16x8*)(in + (size_t)row * 2048 + t * 8);
    float xv[8];
#pragma unroll
    for (int e = 0; e < 8; e++) xv[e] = bf2f(xr[e]);
    float ss = 0.f;
#pragma unroll
    for (int e = 0; e < 8; e++) ss += xv[e] * xv[e];
#pragma unroll
    for (int m = 1; m < 64; m <<= 1) ss += __shfl_xor(ss, m, 64);
    __shared__ float red[4];
    if ((t & 63) == 0) red[t >> 6] = ss;
    __syncthreads();
    const float tot = red[0] + red[1] + red[2] + red[3];
    const float r = rsqrtf(tot * (1.0f / 2048.0f) + 1e-6f);
    const int s = row & 2047, b = row >> 11;
    const int d0 = t * 8, hd0 = d0 & 127, h = d0 >> 7;
    float4 c0 = ((const float4*)(fc + s * 128 + hd0))[0];
    float4 c1 = ((const float4*)(fc + s * 128 + hd0))[1];
    float4 s0 = ((const float4*)(fs + s * 128 + hd0))[0];
    float4 s1 = ((const float4*)(fs + s * 128 + hd0))[1];
    float4 w0 = ((const float4*)(wv + d0))[0];
    float4 w1 = ((const float4*)(wv + d0))[1];
    float wn[8] = {w0.x, w0.y, w0.z, w0.w, w1.x, w1.y, w1.z, w1.w};
    float xn[8];
#pragma unroll
    for (int e = 0; e < 8; e++) xn[e] = xv[e] * wn[e] * r;
    float o[8];
    o[0] = xn[0] * c0.x - xn[1] * s0.y;  o[1] = xn[0] * s0.y + xn[1] * c0.x;
    o[2] = xn[2] * c0.z - xn[3] * s0.w;  o[3] = xn[2] * s0.w + xn[3] * c0.z;
    o[4] = xn[4] * c1.x - xn[5] * s1.y;  o[5] = xn[4] * s1.y + xn[5] * c1.x;
    o[6] = xn[6] * c1.z - xn[7] * s1.w;  o[7] = xn[6] * s1.w + xn[7] * c1.z;
    u16x8 pk;
#pragma unroll
    for (int e = 0; e < 8; e++) pk[e] = f2bf(o[e] * qs);
    *(u16x8*)(out + ((size_t)((b * 16 + h) * 2048 + s)) * 128 + hd0) = pk;
}

// -------------------------------------------------------------- flash attn
// R9/R12 structure (proven) + K-row permutation rho (swap 4-row chunks
// {4-7}<->{8-11} within each 16-row group, applied to the STAGING SOURCE row).
// With rho, lane (q,h) holds S-scores for keys 8h..8h+7 / 16+8h.. etc IN
// ORDER, so PV's B-fragment is the lane's OWN packed words W[4c..4c+3] —
// the 16 shfl_xor half-exchanges per tile are eliminated (only the max and
// final-lsum shfl remain). V layout and all sync structure unchanged.
__global__ __launch_bounds__(256, 2) void attn(
    const unsigned short* __restrict__ Qr, const unsigned short* __restrict__ Kr,
    const unsigned short* __restrict__ Vt, unsigned short* __restrict__ Ao) {
    __shared__ unsigned short Kl[2][64 * 128];
    __shared__ unsigned short Vl[2][128 * 64];
    const int t = threadIdx.x, w = t >> 6, l = t & 63;
    const int ql = l & 31, h = l >> 5;
    const int bid = blockIdx.x;
    const int xcd = bid & 7, idx = bid >> 3;
    const int bh = xcd * 4 + (idx >> 4);
    const int q0 = (idx & 15) * 128 + w * 32;
    const int b = bh >> 4, head = bh & 15;

    const unsigned short* Qp = Qr + ((size_t)bh * 2048 + q0) * 128;
    bf16x8 qf[8];
#pragma unroll
    for (int c8 = 0; c8 < 8; c8++)
        qf[c8] = *(const bf16x8*)(Qp + ql * 128 + c8 * 16 + h * 8);

    f32x16 accO[4];
#pragma unroll
    for (int dt = 0; dt < 4; dt++)
#pragma unroll
        for (int r = 0; r < 16; r++) accO[dt][r] = 0.f;
    float mj = -1e30f, ljp = 0.f;

    const unsigned short* Kb = Kr + (size_t)bh * 2048 * 128;
    const unsigned short* Vb = Vt + (size_t)bh * 128 * 2048;
    const int krow = t >> 4, kseg = (t & 15) ^ (krow & 7);
    const int vrow = t >> 3, vseg = (t & 7) ^ (vrow & 7);

    auto STAGE = [&](int buf, int kv0) {
        char* kd = (char*)&Kl[buf][0] + w * 1024;
        char* vd = (char*)&Vl[buf][0] + w * 1024;
#pragma unroll
        for (int c = 0; c < 4; c++) {
            // rho: LDS row j = c*16+krow sources global key row rho(j)
            const int j = c * 16 + krow;
            const int ch = (j >> 2) & 3;
            const int jp = j + (ch == 1 ? 4 : (ch == 2 ? -4 : 0));
            gload16(Kb + (size_t)(kv0 + jp) * 128 + kseg * 8, kd + c * 4096);
        }
#pragma unroll
        for (int c = 0; c < 4; c++)
            gload16(Vb + (size_t)(c * 32 + vrow) * 2048 + kv0 + vseg * 8, vd + c * 4096);
    };

    const int qx = ql & 7;
    STAGE(0, 0);
    __syncthreads();
    int cur = 0;
    for (int it = 0; it < 32; ++it) {
        if (it < 31) STAGE(cur ^ 1, (it + 1) * 64);
        f32x16 S0, S1;
#pragma unroll
        for (int r = 0; r < 16; r++) { S0[r] = 0.f; S1[r] = 0.f; }
        __builtin_amdgcn_s_setprio(1);
#pragma unroll
        for (int c8 = 0; c8 < 8; c8++) {
            const int sg = ((c8 * 2 + h) ^ qx) << 4;
            bf16x8 k0 = *(const bf16x8*)((const char*)&Kl[cur][0] + ql * 256 + sg);
            bf16x8 k1 = *(const bf16x8*)((const char*)&Kl[cur][0] + (32 + ql) * 256 + sg);
            S0 = __builtin_amdgcn_mfma_f32_32x32x16_bf16(k0, qf[c8], S0, 0, 0, 0);
            S1 = __builtin_amdgcn_mfma_f32_32x32x16_bf16(k1, qf[c8], S1, 0, 0, 0);
        }
        __builtin_amdgcn_s_setprio(0);
        // balanced max tree (permutation-invariant)
        float tq[8];
#pragma unroll
        for (int i = 0; i < 8; i++)
            tq[i] = fmaxf(fmaxf(S0[2 * i], S0[2 * i + 1]),
                          fmaxf(S1[2 * i], S1[2 * i + 1]));
        const float mloc = fmaxf(
            fmaxf(fmaxf(tq[0], tq[1]), fmaxf(tq[2], tq[3])),
            fmaxf(fmaxf(tq[4], tq[5]), fmaxf(tq[6], tq[7])));
        const float mx = fmaxf(mloc, __shfl_xor(mloc, 32, 64));
        if (!__all(mx <= mj + 8.0f)) {          // T13 defer-max, THR=8
            const float mn = fmaxf(mj, mx);
            const float corr = exp2f(mj - mn);
            mj = mn;
            ljp *= corr;
#pragma unroll
            for (int dt = 0; dt < 4; dt++)
#pragma unroll
                for (int r = 0; r < 16; r++) accO[dt][r] *= corr;
        }
        unsigned W[16];
        float lsum = 0.f;
#pragma unroll
        for (int i = 0; i < 8; i++) {
            const float pa = exp2f(S0[2 * i] - mj);
            const float pb = exp2f(S0[2 * i + 1] - mj);
            W[i] = cvtpk(pa, pb);
            lsum += pa + pb;
        }
#pragma unroll
        for (int i = 0; i < 8; i++) {
            const float pa = exp2f(S1[2 * i] - mj);
            const float pb = exp2f(S1[2 * i + 1] - mj);
            W[8 + i] = cvtpk(pa, pb);
            lsum += pa + pb;
        }
        ljp += lsum;
        // ---- PV: B-fragments are the lane's own W words (no exchange)
#pragma unroll
        for (int c = 0; c < 2; c++) {
            union U { unsigned u[4]; bf16x8 v; };
            U F, G;
            F.u[0] = W[c * 8 + 0]; F.u[1] = W[c * 8 + 1];
            F.u[2] = W[c * 8 + 2]; F.u[3] = W[c * 8 + 3];
            G.u[0] = W[c * 8 + 4]; G.u[1] = W[c * 8 + 5];
            G.u[2] = W[c * 8 + 6]; G.u[3] = W[c * 8 + 7];
            __builtin_amdgcn_s_setprio(1);
#pragma unroll
            for (int dt = 0; dt < 4; dt++) {
                const int sg = (((2 * c) * 2 + h) ^ qx) << 4;
                bf16x8 vf = *(const bf16x8*)((const char*)&Vl[cur][0] + (dt * 32 + ql) * 128 + sg);
                accO[dt] = __builtin_amdgcn_mfma_f32_32x32x16_bf16(vf, F.v, accO[dt], 0, 0, 0);
            }
#pragma unroll
            for (int dt = 0; dt < 4; dt++) {
                const int sg = (((2 * c + 1) * 2 + h) ^ qx) << 4;
                bf16x8 vf = *(const bf16x8*)((const char*)&Vl[cur][0] + (dt * 32 + ql) * 128 + sg);
                accO[dt] = __builtin_amdgcn_mfma_f32_32x32x16_bf16(vf, G.v, accO[dt], 0, 0, 0);
            }
            __builtin_amdgcn_s_setprio(0);
        }
        __syncthreads();
        cur ^= 1;
    }
    const float lj = ljp + __shfl_xor(ljp, 32, 64);
    const float inv = 1.0f / lj;
    unsigned short* ob = Ao + ((size_t)(b * 2048 + q0 + ql)) * 2048 + head * 128;
#pragma unroll
    for (int dt = 0; dt < 4; dt++)
#pragma unroll
        for (int i = 0; i < 8; i++) {
            const float a = accO[dt][2 * i] * inv;
            const float c = accO[dt][2 * i + 1] * inv;
            const int d = dt * 32 + ((2 * i) & 3) + 8 * (i >> 1) + 4 * h;
            *(unsigned*)(ob + d) = cvtpk(a, c);
        }
}

// ------------------------------------------------------------------ launch
extern "C" void kernel_launch(void* const* d_in, const int* in_sizes, int n_in,
                              void* d_out, int out_size, void* d_ws, size_t ws_size,
                              hipStream_t stream) {
    const float* hs  = (const float*)d_in[0];
    const float* fc  = (const float*)d_in[1];
    const float* fs  = (const float*)d_in[2];
    const float* Wq  = (const float*)d_in[3];
    const float* bq  = (const float*)d_in[4];
    const float* Wk  = (const float*)d_in[5];
    const float* bk  = (const float*)d_in[6];
    const float* Wv  = (const float*)d_in[7];
    const float* bv  = (const float*)d_in[8];
    const float* nqw = (const float*)d_in[9];
    const float* nkw = (const float*)d_in[10];
    const float* Wo  = (const float*)d_in[11];
    const float* bo  = (const float*)d_in[12];
    float* out = (float*)d_out;

    char* p = (char*)d_ws;
    unsigned short* hs16 = (unsigned short*)p; p += (size_t)8388608 * 2;
    unsigned short* Wq16 = (unsigned short*)p; p += (size_t)4194304 * 2;
    unsigned short* Wk16 = (unsigned short*)p; p += (size_t)4194304 * 2;
    unsigned short* Wv16 = (unsigned short*)p; p += (size_t)4194304 * 2;
    unsigned short* Wo16 = (unsigned short*)p; p += (size_t)4194304 * 2;
    unsigned short* qh = (unsigned short*)p;   p += (size_t)8388608 * 2;
    unsigned short* kh = (unsigned short*)p;   p += (size_t)8388608 * 2;
    unsigned short* Qr = (unsigned short*)p;   p += (size_t)8388608 * 2;
    unsigned short* Kr = (unsigned short*)p;   p += (size_t)8388608 * 2;
    unsigned short* Vt = (unsigned short*)p;   p += (size_t)8388608 * 2;
    unsigned short* Ao = (unsigned short*)p;   p += (size_t)8388608 * 2;
    (void)ws_size; (void)in_sizes; (void)n_in; (void)out_size;

    cvt_all<<<6144, 256, 0, stream>>>(hs, Wq, Wk, Wv, Wo,
                                      hs16, Wq16, Wk16, Wv16, Wo16);
    gemm_qkv<<<768, 512, 0, stream>>>(hs16, Wq16, Wk16, Wv16,
                                      bq, bk, bv, qh, kh, Vt);
    norm_rope<<<dim3(4096, 2), 256, 0, stream>>>(qh, kh, nqw, nkw, fc, fs, Qr, Kr);
    attn<<<512, 256, 0, stream>>>(Qr, Kr, Vt, Ao);
    gemm_o<<<256, 512, 0, stream>>>(Ao, Wo16, bo, out);
}